// Round 13
// baseline (148.132 us; speedup 1.0000x reference)
//
#include <hip/hip_runtime.h>
#include <hip/hip_fp16.h>

// Problem: inputs (8, 64, 16, 32, 32) fp32, embedding (1024, 64) fp32
#define THW    16384
#define NTOT   131072
#define KDIM   1024
#define CDIM   64
#define QELEMS 8388608          // 8*64*16*32*32
#define LOSS_OFF 8388608
#define IDX_OFF  8388610
#define BN     128              // queries per block

typedef _Float16 half8   __attribute__((ext_vector_type(8)));
typedef _Float16 half4_t __attribute__((ext_vector_type(4)));
typedef float    f32x4   __attribute__((ext_vector_type(4)));

// ---- prep: zero losses; split E into fp16 hi/lo (lo scaled 2^12) into ONE
// interleaved buffer Ef[tile][slot][lane][8], slots = {h.ch0, h.ch1, l.ch0,
// l.ch1}; tile = 4 KB, linear in the exact lane order vq_main's ds_reads use,
// so global_load_lds (wave-uniform base + lane*16) can stage it untouched.
// me2h[row] = -0.5*||e||^2 (seeds the hh MFMA chain; staged to LDS by main).
__global__ __launch_bounds__(256) void vq_prep(const float* __restrict__ emb,
        _Float16* __restrict__ Ef, float* __restrict__ me2h,
        float* __restrict__ out) {
    const int t = threadIdx.x;
    if (blockIdx.x == 0 && t == 0) { out[LOSS_OFF] = 0.f; out[LOSS_OFF + 1] = 0.f; }
    const int ln   = t >> 4;
    const int g    = t & 15;
    const int tile = blockIdx.x;
    const int row  = tile * 16 + ln;
    const int c0   = g * 4;
    float4 v = *(const float4*)(emb + (size_t)row * CDIM + c0);
    const float xs[4] = {v.x, v.y, v.z, v.w};
    half4_t h, l;
    float s = 0.f;
    #pragma unroll
    for (int j = 0; j < 4; ++j) {
        const _Float16 hj = (_Float16)xs[j];
        const _Float16 lj = (_Float16)((xs[j] - (float)hj) * 4096.0f);
        h[j] = hj; l[j] = lj;
        s = fmaf(xs[j], xs[j], s);
    }
    const int ch = c0 >> 5;
    const int lq = (c0 & 31) >> 3;
    const int j0 = c0 & 7;
    const int fl = lq * 16 + ln;
    *(half4_t*)(Ef + (((size_t)tile * 4 + ch)     * 64 + fl) * 8 + j0) = h;
    *(half4_t*)(Ef + (((size_t)tile * 4 + 2 + ch) * 64 + fl) * 8 + j0) = l;
    #pragma unroll
    for (int off = 1; off < 16; off <<= 1) s += __shfl_xor(s, off, 64);
    if (g == 0) me2h[row] = -0.5f * s;
}

// ---- main: r6 compute structure (2x2 wave split), but ZERO in-loop
// barriers: each wave stages its own parity tiles into a PRIVATE 3 x 4 KB
// LDS ring, self-paced on counted vmcnt (4 global_load_lds per tile;
// depth-2 => vmcnt(8) steady; in-order retirement). The vmcnt ledger
// contains ONLY explicit global_load_lds (r9/r10 lesson: a compiler-
// scheduled VMEM load inside the window breaks the count) — e2 seeds come
// from an LDS copy (lgkm domain) made cross-wave-visible by ONE pre-loop
// vmcnt(0)+barrier. 12 self-paced waves/CU -> pipes see time-averaged
// demand instead of barrier-lockstep bursts.
__global__ __launch_bounds__(256, 3) void vq_main(const float* __restrict__ in,
        const float* __restrict__ emb,
        const _Float16* __restrict__ Ef,
        const float* __restrict__ me2h, float* __restrict__ out) {

    __shared__ char smem[53248];
    // phase 1: Xs[128][68] @ 0 (34816 B)
    // loop:    wave w private ring @ w*12288 (3 x 4096); me2l @ 49152 (4 KB)
    // post:    bv @ 0 (512), bj @ 512, idxs @ 1024, wsum @ 1536,
    //          Q[128][68] @ 2048 — all written after the post-loop barrier
    float (*Xs)[68] = (float (*)[68])smem;
    float (*Q)[68]  = (float (*)[68])(smem + 2048);
    float* bv   = (float*)smem;
    int*   bj   = (int*)(smem + 512);
    int*   idxs = (int*)(smem + 1024);
    float* wsum = (float*)(smem + 1536);
    const char* me2l = (const char*)smem + 49152;

    const int tid  = threadIdx.x;
    const int lane = tid & 63;
    const int w    = tid >> 6;
    const int wk   = w & 1;         // tile parity this wave computes
    const int wq   = w >> 1;        // query half this wave computes
    const int ln   = lane & 15;
    const int lq   = lane >> 4;

    const int n0   = blockIdx.x * BN;
    const int bb   = n0 >> 14;
    const int thw0 = n0 & (THW - 1);
    const float* inb = in  + (size_t)bb * CDIM * THW + thw0;
    float*      outb = out + (size_t)bb * CDIM * THW + thw0;

    // ---- stage X tile ([n][c] transpose) ----
    {
        const int nl = tid & 127;
        const int hf = tid >> 7;
        #pragma unroll 8
        for (int r = 0; r < 32; ++r) {
            const int c = hf * 32 + r;
            Xs[nl][c] = inb[(size_t)c * THW + nl];
        }
    }
    __syncthreads();

    // ---- B fragments (fp16 hi/lo) + ||x||^2 in registers: 4 qg groups ----
    half8 Bh[4][2], Bl[4][2];
    float x2r[4];
    #pragma unroll
    for (int qg = 0; qg < 4; ++qg) {
        const int q = wq * 64 + qg * 16 + ln;
        float s = 0.f;
        #pragma unroll
        for (int ch = 0; ch < 2; ++ch) {
            const float* xp = &Xs[q][ch * 32 + lq * 8];
            const float4 xa = *(const float4*)(xp);
            const float4 xb = *(const float4*)(xp + 4);
            const float xv[8] = {xa.x, xa.y, xa.z, xa.w, xb.x, xb.y, xb.z, xb.w};
            #pragma unroll
            for (int j = 0; j < 8; ++j) {
                const _Float16 h = (_Float16)xv[j];
                const _Float16 l = (_Float16)((xv[j] - (float)h) * 4096.0f);
                Bh[qg][ch][j] = h;
                Bl[qg][ch][j] = l;
                s = fmaf(xv[j], xv[j], s);
            }
        }
        s += __shfl_xor(s, 16, 64);     // fold the 4 lq-quads: full ||x||^2
        s += __shfl_xor(s, 32, 64);
        x2r[qg] = s;
    }
    __syncthreads();    // Xs dead -> rings may be written; me2l region free

    // ---- me2 -> LDS (each wave copies its quarter), then make it
    // cross-wave visible: own vmcnt(0) drain + one barrier. This is the
    // ONLY barrier between here and the end of the loop.
    __builtin_amdgcn_global_load_lds(
        (const unsigned int*)((const char*)me2h + w * 1024 + lane * 16),
        (unsigned int*)(smem + 49152 + w * 1024), 16, 0, 0);
    asm volatile("s_waitcnt vmcnt(0)" ::: "memory");
    __syncthreads();

    char* ring = smem + w * 12288;                  // wave-private ring
    const char* Efb = (const char*)Ef + (size_t)(lane * 16);

    float bests[4] = {-3.4e38f, -3.4e38f, -3.4e38f, -3.4e38f};
    int   besti[4] = {0, 0, 0, 0};

// stage tile kt = 2*T + wk (private, 4 x 1 KB -> 4 vmcnt ops) into slot SL
#define STAGE(T, SL)                                                          \
    {   const char* gsrc = Efb + (size_t)(2 * (T) + wk) * 4096;               \
        char* ldst = ring + (SL) * 4096;                                      \
        __builtin_amdgcn_global_load_lds((const unsigned int*)(gsrc),         \
                (unsigned int*)(ldst), 16, 0, 0);                             \
        __builtin_amdgcn_global_load_lds((const unsigned int*)(gsrc + 1024),  \
                (unsigned int*)(ldst + 1024), 16, 0, 0);                      \
        __builtin_amdgcn_global_load_lds((const unsigned int*)(gsrc + 2048),  \
                (unsigned int*)(ldst + 2048), 16, 0, 0);                      \
        __builtin_amdgcn_global_load_lds((const unsigned int*)(gsrc + 3072),  \
                (unsigned int*)(ldst + 3072), 16, 0, 0);                      \
    }

// compute tile kt = 2*T + wk from ring slot SL (r6's exact COMP: hh 2-dep
// seeded by e2 from me2l, cr 4-dep, fold fmaf(2^-12, cr, hh))
#define COMP(T, SL)                                                           \
    {   const half8* A = (const half8*)(ring + (SL) * 4096);                  \
        const half8 ah0 = A[lane];                                            \
        const half8 ah1 = A[64 + lane];                                       \
        const half8 al0 = A[128 + lane];                                      \
        const half8 al1 = A[192 + lane];                                      \
        const int kt = 2 * (T) + wk;                                          \
        const f32x4 e2v = *(const f32x4*)(me2l + kt * 64 + lq * 16);          \
        const int kb = kt * 16;                                               \
        __builtin_amdgcn_s_setprio(1);                                        \
        _Pragma("unroll")                                                     \
        for (int qg = 0; qg < 4; ++qg) {                                      \
            f32x4 hh = e2v;                                                   \
            hh = __builtin_amdgcn_mfma_f32_16x16x32_f16(ah0, Bh[qg][0], hh, 0, 0, 0); \
            hh = __builtin_amdgcn_mfma_f32_16x16x32_f16(ah1, Bh[qg][1], hh, 0, 0, 0); \
            f32x4 cr = {0.f, 0.f, 0.f, 0.f};                                  \
            cr = __builtin_amdgcn_mfma_f32_16x16x32_f16(ah0, Bl[qg][0], cr, 0, 0, 0); \
            cr = __builtin_amdgcn_mfma_f32_16x16x32_f16(al0, Bh[qg][0], cr, 0, 0, 0); \
            cr = __builtin_amdgcn_mfma_f32_16x16x32_f16(ah1, Bl[qg][1], cr, 0, 0, 0); \
            cr = __builtin_amdgcn_mfma_f32_16x16x32_f16(al1, Bh[qg][1], cr, 0, 0, 0); \
            _Pragma("unroll")                                                 \
            for (int r = 0; r < 4; ++r) {                                     \
                const float cv = fmaf(2.44140625e-4f, cr[r], hh[r]);          \
                if (cv > bests[qg]) { bests[qg] = cv; besti[qg] = kb + r; }    \
            }                                                                 \
        }                                                                     \
        __builtin_amdgcn_s_setprio(0);                                        \
    }

// counted waits: rule-#18 fence (sched_barrier) pins the following ds_reads
#define WAITV8 { asm volatile("s_waitcnt vmcnt(8)" ::: "memory"); __builtin_amdgcn_sched_barrier(0); }
#define WAITV4 { asm volatile("s_waitcnt vmcnt(4)" ::: "memory"); __builtin_amdgcn_sched_barrier(0); }
#define WAITV0 { asm volatile("s_waitcnt vmcnt(0)" ::: "memory"); __builtin_amdgcn_sched_barrier(0); }

    // self-paced loop: at step t, issue stage(t+2), wait vmcnt(8) (retires
    // stage(t): {t+1, t+2} = 8 ops remain in flight), compute tile t.
    // Ledger contains ONLY the STAGE global_load_lds ops (4 per tile).
    STAGE(0, 0)
    STAGE(1, 1)
    #pragma unroll 1
    for (int t0 = 0; t0 < 30; t0 += 3) {
        STAGE(t0 + 2, 2) WAITV8 COMP(t0,     0)
        STAGE(t0 + 3, 0) WAITV8 COMP(t0 + 1, 1)
        STAGE(t0 + 4, 1) WAITV8 COMP(t0 + 2, 2)
    }
    // t=30: outstanding {S30,S31}=8; vmcnt(4) retires S30
    WAITV4 COMP(30, 0)
    WAITV0 COMP(31, 1)

    besti[0] += lq * 4;     // full code index = kt*16 + lq*4 + r
    besti[1] += lq * 4;
    besti[2] += lq * 4;
    besti[3] += lq * 4;

    // ---- wave-internal argmax reduce across the 4 row-quads ----
    #pragma unroll
    for (int qg = 0; qg < 4; ++qg) {
        #pragma unroll
        for (int msk = 16; msk <= 32; msk <<= 1) {
            const float ov = __shfl_xor(bests[qg], msk, 64);
            const int   oi = __shfl_xor(besti[qg], msk, 64);
            if (ov > bests[qg] || (ov == bests[qg] && oi < besti[qg])) {
                bests[qg] = ov; besti[qg] = oi;
            }
        }
    }

    // ---- cross-wave combine: wk=1 publishes, wk=0 merges (x2 in regs) ----
    __syncthreads();    // all waves out of their rings; bv/bj space free
    if (wk == 1 && lq == 0) {
        #pragma unroll
        for (int qg = 0; qg < 4; ++qg) {
            const int q = wq * 64 + qg * 16 + ln;
            bv[q] = bests[qg];
            bj[q] = besti[qg];
        }
    }
    __syncthreads();

    float lsum = 0.f;
    if (wk == 0 && lq == 0) {
        #pragma unroll
        for (int qg = 0; qg < 4; ++qg) {
            const int q = wq * 64 + qg * 16 + ln;
            const float ov = bv[q];
            const int   oi = bj[q];
            if (ov > bests[qg] || (ov == bests[qg] && oi < besti[qg])) {
                bests[qg] = ov; besti[qg] = oi;
            }
            idxs[q] = besti[qg];
            out[IDX_OFF + n0 + q] = (float)besti[qg];
            // d = -2*s ; loss term = d + ||x||^2
            lsum += fmaf(-2.0f, bests[qg], x2r[qg]);
        }
    }
    #pragma unroll
    for (int off = 32; off > 0; off >>= 1) lsum += __shfl_down(lsum, off, 64);
    if (lane == 0) wsum[w] = lsum;
    __syncthreads();    // idxs + wsum visible
    if (tid == 0) {
        const float s = wsum[0] + wsum[1] + wsum[2] + wsum[3];
        atomicAdd(&out[LOSS_OFF],     s * (1.0f  / (float)QELEMS));
        atomicAdd(&out[LOSS_OFF + 1], s * (0.25f / (float)QELEMS));
    }

    // ---- epilogue: gather code rows into LDS (Q @ 2048), transpose-write ----
    {
        const int q  = tid >> 1;
        const int hf = tid & 1;
        const float* er = emb + (size_t)idxs[q] * CDIM + hf * 32;
        #pragma unroll
        for (int j = 0; j < 8; ++j) {
            const float4 v = *(const float4*)(er + 4 * j);
            *(float4*)(&Q[q][hf * 32 + 4 * j]) = v;
        }
    }
    __syncthreads();
    {
        const int nl = tid & 127;
        const int cb = tid >> 7;
        #pragma unroll 8
        for (int r = 0; r < 32; ++r) {
            const int c = 2 * r + cb;
            outb[(size_t)c * THW + nl] = Q[nl][c];
        }
    }
#undef STAGE
#undef COMP
#undef WAITV8
#undef WAITV4
#undef WAITV0
}

extern "C" void kernel_launch(void* const* d_in, const int* in_sizes, int n_in,
                              void* d_out, int out_size, void* d_ws, size_t ws_size,
                              hipStream_t stream) {
    const float* in  = (const float*)d_in[0];   // (8, 64, 16, 32, 32) fp32
    const float* emb = (const float*)d_in[1];   // (1024, 64) fp32
    float* out = (float*)d_out;
    _Float16* Ef   = (_Float16*)d_ws;                       // 64 tiles * 4 KB = 256 KB
    float*    me2h = (float*)((char*)d_ws + 262144);        // 1024 floats = -0.5*||e||^2

    vq_prep<<<KDIM / 16, 256, 0, stream>>>(emb, Ef, me2h, out);
    vq_main<<<NTOT / BN, 256, 0, stream>>>(in, emb, Ef, me2h, out);
}

// Round 14
// 148.095 us; speedup vs baseline: 1.0003x; 1.0003x over previous
//
#include <hip/hip_runtime.h>
#include <hip/hip_fp16.h>

// Problem: inputs (8, 64, 16, 32, 32) fp32, embedding (1024, 64) fp32
#define THW    16384
#define NTOT   131072
#define KDIM   1024
#define CDIM   64
#define QELEMS 8388608          // 8*64*16*32*32
#define LOSS_OFF 8388608
#define IDX_OFF  8388610
#define BN     128              // queries per block

typedef _Float16 half8   __attribute__((ext_vector_type(8)));
typedef float    f32x4   __attribute__((ext_vector_type(4)));
typedef float    f32x16  __attribute__((ext_vector_type(16)));

// ---- prep for 32x32x16 MFMA: split E into fp16 hi/lo (lo scaled 2^12).
// Tile = 32 codes = 8 KB: slots {hi s=0..3, lo s=0..3}, each slot 1 KB laid
// out linear in lane order: value(lane, j) = e_x[tile*32 + (lane&31)]
//                                           [s*16 + (lane>>5)*8 + j]
// (A-fragment layout of mfma_f32_32x32x16_f16: row=lane&31, k=(lane>>5)*8+j).
// me2h[code] = -0.5*||e||^2 (hh-chain seed; staged to LDS by main).
__global__ __launch_bounds__(256) void vq_prep(const float* __restrict__ emb,
        _Float16* __restrict__ Ef, float* __restrict__ me2h,
        float* __restrict__ out) {
    __shared__ float sm[4][32];
    const int t = threadIdx.x;
    if (blockIdx.x == 0 && t == 0) { out[LOSS_OFF] = 0.f; out[LOSS_OFF + 1] = 0.f; }
    const int lane = t & 63;
    const int sw   = t >> 6;            // slice s (one per wave)
    const int tile = blockIdx.x;        // 32 blocks of 32 codes
    const int code = tile * 32 + (lane & 31);
    const int hi5  = lane >> 5;
    const int c0   = sw * 16 + hi5 * 8;
    const float* ep = emb + (size_t)code * CDIM + c0;
    const float4 va = *(const float4*)ep;
    const float4 vb = *(const float4*)(ep + 4);
    const float xs[8] = {va.x, va.y, va.z, va.w, vb.x, vb.y, vb.z, vb.w};
    half8 h, l;
    float p = 0.f;
    #pragma unroll
    for (int j = 0; j < 8; ++j) {
        const _Float16 hj = (_Float16)xs[j];
        h[j] = hj;
        l[j] = (_Float16)((xs[j] - (float)hj) * 4096.0f);
        p = fmaf(xs[j], xs[j], p);
    }
    *(half8*)(Ef + (((size_t)tile * 8 + sw)     * 64 + lane) * 8) = h;
    *(half8*)(Ef + (((size_t)tile * 8 + 4 + sw) * 64 + lane) * 8) = l;
    p += __shfl_xor(p, 32, 64);         // sum the two c-halves of this slice
    if (lane < 32) sm[sw][lane] = p;
    __syncthreads();
    if (t < 32) me2h[tile * 32 + t] = -0.5f * (sm[0][t] + sm[1][t] + sm[2][t] + sm[3][t]);
}

// ---- main: r6's proven pipeline (2x2 wave split, counted-vmcnt, 3 shared
// buffers, cooperative global_load_lds, e2 in LDS) ported to 32x32x16 MFMA:
// half the MFMA instructions (384/wave vs 768) at 17% lower matrix-cycle
// cost (m119: 8.07 cyc/32K FLOP vs 4.85/16K). Step stages a 16 KB tile-pair
// (4 vmcnt ops); wave (wq,wk) computes 32-code tile 2s+wk for its 64
// queries. vmcnt ledger: ONLY explicit global_load_lds ops (r10 lesson).
__global__ __launch_bounds__(256, 3) void vq_main(const float* __restrict__ in,
        const float* __restrict__ emb,
        const _Float16* __restrict__ Ef,
        const float* __restrict__ me2h, float* __restrict__ out) {

    __shared__ char smem[53248];
    // phase 1: Xs[128][68] @ 0 (34816 B)
    // loop:    buf0/1/2 @ 0/16384/32768 (16 KB each); me2l @ 49152 (4 KB)
    // post:    bv @ 0 (512), bj @ 512, idxs @ 1024, wsum @ 1536,
    //          Q[128][68] @ 2048 — all written after the post-loop barrier
    float (*Xs)[68] = (float (*)[68])smem;
    float (*Q)[68]  = (float (*)[68])(smem + 2048);
    float* bv   = (float*)smem;
    int*   bj   = (int*)(smem + 512);
    int*   idxs = (int*)(smem + 1024);
    float* wsum = (float*)(smem + 1536);
    const char* me2l = (const char*)smem + 49152;

    const int tid  = threadIdx.x;
    const int lane = tid & 63;
    const int w    = tid >> 6;
    const int wk   = w & 1;         // tile parity this wave computes
    const int wq   = w >> 1;        // query half this wave computes
    const int hi5  = lane >> 5;

    const int n0   = blockIdx.x * BN;
    const int bb   = n0 >> 14;
    const int thw0 = n0 & (THW - 1);
    const float* inb = in  + (size_t)bb * CDIM * THW + thw0;
    float*      outb = out + (size_t)bb * CDIM * THW + thw0;

    // ---- stage X tile ([n][c] transpose) ----
    {
        const int nl = tid & 127;
        const int hf = tid >> 7;
        #pragma unroll 8
        for (int r = 0; r < 32; ++r) {
            const int c = hf * 32 + r;
            Xs[nl][c] = inb[(size_t)c * THW + nl];
        }
    }
    __syncthreads();

    // ---- B fragments for 32x32x16 (col=lane&31, k=(lane>>5)*8+j):
    // 2 query groups x 4 K-slices; ||x||^2 via one xor-32 shuffle ----
    half8 Bh[2][4], Bl[2][4];
    float x2r[2];
    #pragma unroll
    for (int g = 0; g < 2; ++g) {
        const int q = wq * 64 + g * 32 + (lane & 31);
        float p = 0.f;
        #pragma unroll
        for (int sl = 0; sl < 4; ++sl) {
            const float* xp = &Xs[q][sl * 16 + hi5 * 8];
            const float4 xa = *(const float4*)(xp);
            const float4 xb = *(const float4*)(xp + 4);
            const float xv[8] = {xa.x, xa.y, xa.z, xa.w, xb.x, xb.y, xb.z, xb.w};
            #pragma unroll
            for (int j = 0; j < 8; ++j) {
                const _Float16 h = (_Float16)xv[j];
                Bh[g][sl][j] = h;
                Bl[g][sl][j] = (_Float16)((xv[j] - (float)h) * 4096.0f);
                p = fmaf(xv[j], xv[j], p);
            }
        }
        p += __shfl_xor(p, 32, 64);     // other 32 channels live on lane^32
        x2r[g] = p;
    }
    __syncthreads();    // Xs dead -> smem becomes bufs + me2l

    // me2 -> LDS (4 KB; op #1 of the vmcnt ledger)
    __builtin_amdgcn_global_load_lds(
        (const unsigned int*)((const char*)me2h + w * 1024 + lane * 16),
        (unsigned int*)(smem + 49152 + w * 1024), 16, 0, 0);

    const char* Efb = (const char*)Ef + (size_t)(w * 1024 + lane * 16);

    float bests[2] = {-3.4e38f, -3.4e38f};
    int   besti[2] = {0, 0};

// stage tile-pair K (16 KB = tiles 2K, 2K+1; 4 vmcnt ops) into buffer BI
#define STAGE(K, BI)                                                          \
    {   const char* gsrc = Efb + (size_t)(K) * 16384;                         \
        char* ldst = smem + (BI) * 16384 + w * 1024;                          \
        __builtin_amdgcn_global_load_lds((const unsigned int*)(gsrc),         \
                (unsigned int*)(ldst), 16, 0, 0);                             \
        __builtin_amdgcn_global_load_lds((const unsigned int*)(gsrc + 4096),  \
                (unsigned int*)(ldst + 4096), 16, 0, 0);                      \
        __builtin_amdgcn_global_load_lds((const unsigned int*)(gsrc + 8192),  \
                (unsigned int*)(ldst + 8192), 16, 0, 0);                      \
        __builtin_amdgcn_global_load_lds((const unsigned int*)(gsrc + 12288), \
                (unsigned int*)(ldst + 12288), 16, 0, 0);                     \
    }

// compute tile kt = 2S + wk from buffer BI: per group g, hh (4-chain,
// seeded with -0.5||e||^2) and cross (8-chain, scaled 2^12); fold
// cv = hh + 2^-12*cr with ascending-index strict-> (lowest-k tie-break).
// C/D layout: col=lane&31 (query), row=(r&3)+8*(r>>2)+4*hi5 (code).
#define COMPUTE(S, BI)                                                        \
    {   const char* tb = smem + (BI) * 16384 + wk * 8192;                     \
        const int kt = 2 * (S) + wk;                                          \
        half8 Ah[4], Al[4];                                                   \
        _Pragma("unroll")                                                     \
        for (int sl = 0; sl < 4; ++sl) {                                      \
            Ah[sl] = *(const half8*)(tb + sl * 1024 + lane * 16);             \
            Al[sl] = *(const half8*)(tb + 4096 + sl * 1024 + lane * 16);      \
        }                                                                     \
        const char* eb = me2l + kt * 128 + hi5 * 16;                          \
        const f32x4 e0 = *(const f32x4*)(eb);                                 \
        const f32x4 e1 = *(const f32x4*)(eb + 32);                            \
        const f32x4 e2q = *(const f32x4*)(eb + 64);                           \
        const f32x4 e3 = *(const f32x4*)(eb + 96);                            \
        __builtin_amdgcn_s_setprio(1);                                        \
        _Pragma("unroll")                                                     \
        for (int g = 0; g < 2; ++g) {                                         \
            f32x16 hh;                                                        \
            _Pragma("unroll")                                                 \
            for (int i = 0; i < 4; ++i) {                                     \
                hh[i] = e0[i]; hh[4 + i] = e1[i];                             \
                hh[8 + i] = e2q[i]; hh[12 + i] = e3[i];                       \
            }                                                                 \
            _Pragma("unroll")                                                 \
            for (int sl = 0; sl < 4; ++sl)                                    \
                hh = __builtin_amdgcn_mfma_f32_32x32x16_f16(Ah[sl], Bh[g][sl], hh, 0, 0, 0); \
            f32x16 cr = {0.f};                                                \
            _Pragma("unroll")                                                 \
            for (int sl = 0; sl < 4; ++sl)                                    \
                cr = __builtin_amdgcn_mfma_f32_32x32x16_f16(Ah[sl], Bl[g][sl], cr, 0, 0, 0); \
            _Pragma("unroll")                                                 \
            for (int sl = 0; sl < 4; ++sl)                                    \
                cr = __builtin_amdgcn_mfma_f32_32x32x16_f16(Al[sl], Bh[g][sl], cr, 0, 0, 0); \
            _Pragma("unroll")                                                 \
            for (int r = 0; r < 16; ++r) {                                    \
                const float cv = fmaf(2.44140625e-4f, cr[r], hh[r]);          \
                const int kg = kt * 32 + (r >> 2) * 8 + (r & 3);              \
                if (cv > bests[g]) { bests[g] = cv; besti[g] = kg; }          \
            }                                                                 \
        }                                                                     \
        __builtin_amdgcn_s_setprio(0);                                        \
    }

#define WAIT4 asm volatile("s_waitcnt vmcnt(4)" ::: "memory")
#define WAIT0 asm volatile("s_waitcnt vmcnt(0)" ::: "memory")
#define BAR   __builtin_amdgcn_s_barrier()
#define STEP(S, SB, CB) { WAIT4; BAR; STAGE((S) + 2, SB) COMPUTE(S, CB) }

    // vmcnt ledger: me2l=1 op, STAGE=4 ops. Prologue: me2l+S0+S1 = 9
    // outstanding; first WAIT4 retires me2l+S0. Steady at step S: {S,S+1}=8
    // outstanding -> WAIT4 retires S, leaves S+1 in flight. Never drains.
    STAGE(0, 0)
    STAGE(1, 1)
    #pragma unroll 1
    for (int s0 = 0; s0 < 12; s0 += 3) {
        STEP(s0,     2, 0)
        STEP(s0 + 1, 0, 1)
        STEP(s0 + 2, 1, 2)
    }
    STEP(12, 2, 0)
    STEP(13, 0, 1)
    WAIT4; BAR; COMPUTE(14, 2)
    WAIT0; BAR; COMPUTE(15, 0)

    besti[0] += hi5 * 4;    // full code = kt*32 + (r>>2)*8 + 4*hi5 + (r&3)
    besti[1] += hi5 * 4;

    // ---- wave-internal argmax: lanes L, L^32 share query col, cover
    // complementary code rows -> single xor-32 merge ----
    #pragma unroll
    for (int g = 0; g < 2; ++g) {
        const float ov = __shfl_xor(bests[g], 32, 64);
        const int   oi = __shfl_xor(besti[g], 32, 64);
        if (ov > bests[g] || (ov == bests[g] && oi < besti[g])) {
            bests[g] = ov; besti[g] = oi;
        }
    }

    // ---- cross-wave combine: wk=1 publishes, wk=0 merges (x2 in regs) ----
    __syncthreads();    // all waves out of the buffers; bv/bj space free
    if (wk == 1 && lane < 32) {
        #pragma unroll
        for (int g = 0; g < 2; ++g) {
            const int q = wq * 64 + g * 32 + lane;
            bv[q] = bests[g];
            bj[q] = besti[g];
        }
    }
    __syncthreads();

    float lsum = 0.f;
    if (wk == 0 && lane < 32) {
        #pragma unroll
        for (int g = 0; g < 2; ++g) {
            const int q = wq * 64 + g * 32 + lane;
            const float ov = bv[q];
            const int   oi = bj[q];
            if (ov > bests[g] || (ov == bests[g] && oi < besti[g])) {
                bests[g] = ov; besti[g] = oi;
            }
            idxs[q] = besti[g];
            out[IDX_OFF + n0 + q] = (float)besti[g];
            // d = -2*s ; loss term = d + ||x||^2
            lsum += fmaf(-2.0f, bests[g], x2r[g]);
        }
    }
    #pragma unroll
    for (int off = 32; off > 0; off >>= 1) lsum += __shfl_down(lsum, off, 64);
    if (lane == 0) wsum[w] = lsum;
    __syncthreads();    // idxs + wsum visible
    if (tid == 0) {
        const float s = wsum[0] + wsum[1] + wsum[2] + wsum[3];
        atomicAdd(&out[LOSS_OFF],     s * (1.0f  / (float)QELEMS));
        atomicAdd(&out[LOSS_OFF + 1], s * (0.25f / (float)QELEMS));
    }

    // ---- epilogue: gather code rows into LDS (Q @ 2048), transpose-write ----
    {
        const int q  = tid >> 1;
        const int hf = tid & 1;
        const float* er = emb + (size_t)idxs[q] * CDIM + hf * 32;
        #pragma unroll
        for (int j = 0; j < 8; ++j) {
            const float4 v = *(const float4*)(er + 4 * j);
            *(float4*)(&Q[q][hf * 32 + 4 * j]) = v;
        }
    }
    __syncthreads();
    {
        const int nl = tid & 127;
        const int cb = tid >> 7;
        #pragma unroll 8
        for (int r = 0; r < 32; ++r) {
            const int c = 2 * r + cb;
            outb[(size_t)c * THW + nl] = Q[nl][c];
        }
    }
#undef STAGE
#undef COMPUTE
#undef WAIT4
#undef WAIT0
#undef BAR
#undef STEP
}

extern "C" void kernel_launch(void* const* d_in, const int* in_sizes, int n_in,
                              void* d_out, int out_size, void* d_ws, size_t ws_size,
                              hipStream_t stream) {
    const float* in  = (const float*)d_in[0];   // (8, 64, 16, 32, 32) fp32
    const float* emb = (const float*)d_in[1];   // (1024, 64) fp32
    float* out = (float*)d_out;
    _Float16* Ef   = (_Float16*)d_ws;                       // 32 tiles * 8 KB = 256 KB
    float*    me2h = (float*)((char*)d_ws + 262144);        // 1024 floats = -0.5*||e||^2

    vq_prep<<<KDIM / 32, 256, 0, stream>>>(emb, Ef, me2h, out);
    vq_main<<<NTOT / BN, 256, 0, stream>>>(in, emb, Ef, me2h, out);
}

// Round 15
// 137.668 us; speedup vs baseline: 1.0760x; 1.0757x over previous
//
#include <hip/hip_runtime.h>
#include <hip/hip_fp16.h>

// Problem: inputs (8, 64, 16, 32, 32) fp32, embedding (1024, 64) fp32
#define THW    16384
#define NTOT   131072
#define KDIM   1024
#define CDIM   64
#define QELEMS 8388608          // 8*64*16*32*32
#define LOSS_OFF 8388608
#define IDX_OFF  8388610
#define BN     128              // queries per block

typedef _Float16 half8   __attribute__((ext_vector_type(8)));
typedef _Float16 half4_t __attribute__((ext_vector_type(4)));
typedef float    f32x4   __attribute__((ext_vector_type(4)));

// ---- prep: zero losses; split E into fp16 {hiS, lo} where hiS = 4096*h
// (h = fp16(e), exact exponent shift; 4096*|e|max ~ 18k < 65504) and
// lo = (e - h)*4096. With B-side {xh, xres} this puts ALL six MFMA products
// on ONE 4096x scale -> single accumulator chain, no mid-chain rescale.
// Layout: Ef[tile][slot][lane][8], slots = {hiS.ch0, hiS.ch1, lo.ch0,
// lo.ch1}; tile = 4 KB, linear in the exact lane order vq_main's ds_reads
// use (global_load_lds = wave-uniform base + lane*16).
// me2h[row] = -2048*||e||^2 = 4096*(-0.5||e||^2): seeds the scaled chain.
__global__ __launch_bounds__(256) void vq_prep(const float* __restrict__ emb,
        _Float16* __restrict__ Ef, float* __restrict__ me2h,
        float* __restrict__ out) {
    const int t = threadIdx.x;
    if (blockIdx.x == 0 && t == 0) { out[LOSS_OFF] = 0.f; out[LOSS_OFF + 1] = 0.f; }
    const int ln   = t >> 4;
    const int g    = t & 15;
    const int tile = blockIdx.x;
    const int row  = tile * 16 + ln;
    const int c0   = g * 4;
    float4 v = *(const float4*)(emb + (size_t)row * CDIM + c0);
    const float xs[4] = {v.x, v.y, v.z, v.w};
    half4_t h, l;
    float s = 0.f;
    #pragma unroll
    for (int j = 0; j < 4; ++j) {
        const _Float16 hj = (_Float16)xs[j];
        h[j] = hj * (_Float16)4096.0f;          // exact exponent shift
        l[j] = (_Float16)((xs[j] - (float)hj) * 4096.0f);
        s = fmaf(xs[j], xs[j], s);
    }
    const int ch = c0 >> 5;
    const int lq = (c0 & 31) >> 3;
    const int j0 = c0 & 7;
    const int fl = lq * 16 + ln;
    *(half4_t*)(Ef + (((size_t)tile * 4 + ch)     * 64 + fl) * 8 + j0) = h;
    *(half4_t*)(Ef + (((size_t)tile * 4 + 2 + ch) * 64 + fl) * 8 + j0) = l;
    #pragma unroll
    for (int off = 1; off < 16; off <<= 1) s += __shfl_xor(s, off, 64);
    if (g == 0) me2h[row] = -2048.0f * s;
}

// ---- main: r6's proven structure VERBATIM (2x2 wave split, cooperative
// global_load_lds staging, 3 x 8 KB buffers, counted vmcnt(2), 4 blocks/CU,
// no tail) with a single-scale COMPUTE: acc seeded by 4096*(-0.5||e||^2),
// six MFMAs (ehS*xh + ehS*xres + elS*xh) all at 4096x, fold = bare compare
// (argmax invariant under positive scale; /4096 applied once in the loss).
// Removes the cr zero-init and per-element fmaf merge of the 2-chain form.
__global__ __launch_bounds__(256, 4) void vq_main(const float* __restrict__ in,
        const float* __restrict__ emb,
        const _Float16* __restrict__ Ef,
        const float* __restrict__ me2h, float* __restrict__ out) {

    __shared__ char smem[35840];
    // phase 1: Xs[128][68] @ 0 (34816 B)
    // loop:    buf0/1/2 @ 0/8192/16384 (8 KB each); me2l @ 24576 (4 KB)
    // post:    bv @ 28672 (512), bj @ 29184 (512), idxs @ 34816 (512),
    //          wsum @ 35328; Q[128][68] @ 0 (gather, after loop dead)
    float (*Xs)[68] = (float (*)[68])smem;
    float (*Q)[68]  = (float (*)[68])smem;
    float* bv   = (float*)(smem + 28672);
    int*   bj   = (int*)(smem + 29184);
    int*   idxs = (int*)(smem + 34816);
    float* wsum = (float*)(smem + 35328);
    const char* me2l = (const char*)smem + 24576;

    const int tid  = threadIdx.x;
    const int lane = tid & 63;
    const int w    = tid >> 6;
    const int wk   = w & 1;         // tile parity this wave computes
    const int wq   = w >> 1;        // query half this wave computes
    const int ln   = lane & 15;
    const int lq   = lane >> 4;

    const int n0   = blockIdx.x * BN;
    const int bb   = n0 >> 14;
    const int thw0 = n0 & (THW - 1);
    const float* inb = in  + (size_t)bb * CDIM * THW + thw0;
    float*      outb = out + (size_t)bb * CDIM * THW + thw0;

    // ---- stage X tile ([n][c] transpose) ----
    {
        const int nl = tid & 127;
        const int hf = tid >> 7;
        #pragma unroll 8
        for (int r = 0; r < 32; ++r) {
            const int c = hf * 32 + r;
            Xs[nl][c] = inb[(size_t)c * THW + nl];
        }
    }
    __syncthreads();

    // ---- B fragments {xh, xres} + ||x||^2 in registers: 4 qg groups ----
    half8 Bh[4][2], Bl[4][2];
    float x2r[4];
    #pragma unroll
    for (int qg = 0; qg < 4; ++qg) {
        const int q = wq * 64 + qg * 16 + ln;
        float s = 0.f;
        #pragma unroll
        for (int ch = 0; ch < 2; ++ch) {
            const float* xp = &Xs[q][ch * 32 + lq * 8];
            const float4 xa = *(const float4*)(xp);
            const float4 xb = *(const float4*)(xp + 4);
            const float xv[8] = {xa.x, xa.y, xa.z, xa.w, xb.x, xb.y, xb.z, xb.w};
            #pragma unroll
            for (int j = 0; j < 8; ++j) {
                const _Float16 h = (_Float16)xv[j];
                Bh[qg][ch][j] = h;
                Bl[qg][ch][j] = (_Float16)(xv[j] - (float)h);   // unscaled residual
                s = fmaf(xv[j], xv[j], s);
            }
        }
        s += __shfl_xor(s, 16, 64);     // fold the 4 lq-quads: full ||x||^2
        s += __shfl_xor(s, 32, 64);
        x2r[qg] = s;
    }
    __syncthreads();    // Xs dead -> smem[0..28K) becomes bufs + me2l

    // me2 -> LDS (4 KB, one 16B chunk per thread); retires with stage 0
    __builtin_amdgcn_global_load_lds(
        (const unsigned int*)((const char*)me2h + w * 1024 + lane * 16),
        (unsigned int*)(smem + 24576 + w * 1024), 16, 0, 0);

    const char* Efb = (const char*)Ef + (size_t)(w * 1024 + lane * 16);

    float bests[4] = {-3.4e38f, -3.4e38f, -3.4e38f, -3.4e38f};
    int   besti[4] = {0, 0, 0, 0};

#define STAGE(K, BI)                                                          \
    {   const char* gsrc = Efb + (size_t)(K) * 8192;                          \
        char* ldst = smem + (BI) * 8192 + w * 1024;                           \
        __builtin_amdgcn_global_load_lds((const unsigned int*)(gsrc),         \
                (unsigned int*)(ldst), 16, 0, 0);                             \
        __builtin_amdgcn_global_load_lds((const unsigned int*)(gsrc + 4096),  \
                (unsigned int*)(ldst + 4096), 16, 0, 0);                      \
    }

// each wave computes only the tile of its parity: kt = S*2 + wk.
// Single 4096x-scale chain: acc = 4096*(-0.5||e||^2) + ehS*xh (hh)
// + ehS*xres + elS*xh (cross). Fold: bare compare (scale-invariant).
#define COMPUTE(S, BI)                                                        \
    {   const half8* A = (const half8*)(smem + (BI) * 8192 + wk * 4096);      \
        const half8 ah0 = A[lane];                                            \
        const half8 ah1 = A[64 + lane];                                       \
        const half8 al0 = A[128 + lane];                                      \
        const half8 al1 = A[192 + lane];                                      \
        const int kt = (S) * 2 + wk;                                          \
        const f32x4 e2v = *(const f32x4*)(me2l + kt * 64 + lq * 16);          \
        const int kb = kt * 16;                                               \
        __builtin_amdgcn_s_setprio(1);                                        \
        _Pragma("unroll")                                                     \
        for (int qg = 0; qg < 4; ++qg) {                                      \
            f32x4 acc = e2v;                                                  \
            acc = __builtin_amdgcn_mfma_f32_16x16x32_f16(ah0, Bh[qg][0], acc, 0, 0, 0); \
            acc = __builtin_amdgcn_mfma_f32_16x16x32_f16(ah1, Bh[qg][1], acc, 0, 0, 0); \
            acc = __builtin_amdgcn_mfma_f32_16x16x32_f16(ah0, Bl[qg][0], acc, 0, 0, 0); \
            acc = __builtin_amdgcn_mfma_f32_16x16x32_f16(ah1, Bl[qg][1], acc, 0, 0, 0); \
            acc = __builtin_amdgcn_mfma_f32_16x16x32_f16(al0, Bh[qg][0], acc, 0, 0, 0); \
            acc = __builtin_amdgcn_mfma_f32_16x16x32_f16(al1, Bh[qg][1], acc, 0, 0, 0); \
            _Pragma("unroll")                                                 \
            for (int r = 0; r < 4; ++r) {                                     \
                if (acc[r] > bests[qg]) { bests[qg] = acc[r]; besti[qg] = kb + r; } \
            }                                                                 \
        }                                                                     \
        __builtin_amdgcn_s_setprio(0);                                        \
    }

#define WAIT2 asm volatile("s_waitcnt vmcnt(2)" ::: "memory")
#define WAIT0 asm volatile("s_waitcnt vmcnt(0)" ::: "memory")
#define BAR   __builtin_amdgcn_s_barrier()
#define STEP(S, CB, SB) { WAIT2; BAR; STAGE((S) + 2, SB) COMPUTE(S, CB) }

    // prologue: stage steps 0,1 (buffers 0,1); steady: wait own stage(s)
    // landed (vmcnt(2): stage(s+1) still in flight), barrier (all waves'
    // stage(s) landed AND buffer (s+2)%3 free), issue stage(s+2), compute.
    STAGE(0, 0)
    STAGE(1, 1)
    #pragma unroll 1
    for (int s0 = 0; s0 < 30; s0 += 3) {
        STEP(s0,     0, 2)
        STEP(s0 + 1, 1, 0)
        STEP(s0 + 2, 2, 1)
    }
    WAIT2; BAR; COMPUTE(30, 0)
    WAIT0; BAR; COMPUTE(31, 1)

    besti[0] += lq * 4;     // full code index = kt*16 + lq*4 + r
    besti[1] += lq * 4;
    besti[2] += lq * 4;
    besti[3] += lq * 4;

    // ---- wave-internal argmax reduce across the 4 row-quads ----
    #pragma unroll
    for (int qg = 0; qg < 4; ++qg) {
        #pragma unroll
        for (int msk = 16; msk <= 32; msk <<= 1) {
            const float ov = __shfl_xor(bests[qg], msk, 64);
            const int   oi = __shfl_xor(besti[qg], msk, 64);
            if (ov > bests[qg] || (ov == bests[qg] && oi < besti[qg])) {
                bests[qg] = ov; besti[qg] = oi;
            }
        }
    }

    // ---- cross-wave combine: wk=1 publishes, wk=0 merges (x2 in regs) ----
    if (wk == 1 && lq == 0) {
        #pragma unroll
        for (int qg = 0; qg < 4; ++qg) {
            const int q = wq * 64 + qg * 16 + ln;
            bv[q] = bests[qg];
            bj[q] = besti[qg];
        }
    }
    __syncthreads();    // bv/bj visible; all waves done reading bufs

    float lsum = 0.f;
    if (wk == 0 && lq == 0) {
        #pragma unroll
        for (int qg = 0; qg < 4; ++qg) {
            const int q = wq * 64 + qg * 16 + ln;
            const float ov = bv[q];
            const int   oi = bj[q];
            if (ov > bests[qg] || (ov == bests[qg] && oi < besti[qg])) {
                bests[qg] = ov; besti[qg] = oi;
            }
            idxs[q] = besti[qg];
            out[IDX_OFF + n0 + q] = (float)besti[qg];
            // s = bests/4096 ; d = -2*s ; loss term = d + ||x||^2
            lsum += fmaf(-4.8828125e-4f, bests[qg], x2r[qg]);
        }
    }
    #pragma unroll
    for (int off = 32; off > 0; off >>= 1) lsum += __shfl_down(lsum, off, 64);
    if (lane == 0) wsum[w] = lsum;
    __syncthreads();    // idxs + wsum visible
    if (tid == 0) {
        const float s = wsum[0] + wsum[1] + wsum[2] + wsum[3];
        atomicAdd(&out[LOSS_OFF],     s * (1.0f  / (float)QELEMS));
        atomicAdd(&out[LOSS_OFF + 1], s * (0.25f / (float)QELEMS));
    }

    // ---- epilogue: gather code rows into LDS (Q aliases dead bufs), transpose-write ----
    {
        const int q  = tid >> 1;
        const int hf = tid & 1;
        const float* er = emb + (size_t)idxs[q] * CDIM + hf * 32;
        #pragma unroll
        for (int j = 0; j < 8; ++j) {
            const float4 v = *(const float4*)(er + 4 * j);
            *(float4*)(&Q[q][hf * 32 + 4 * j]) = v;
        }
    }
    __syncthreads();
    {
        const int nl = tid & 127;
        const int cb = tid >> 7;
        #pragma unroll 8
        for (int r = 0; r < 32; ++r) {
            const int c = 2 * r + cb;
            outb[(size_t)c * THW + nl] = Q[nl][c];
        }
    }
#undef STAGE
#undef COMPUTE
#undef WAIT2
#undef WAIT0
#undef BAR
#undef STEP
}

extern "C" void kernel_launch(void* const* d_in, const int* in_sizes, int n_in,
                              void* d_out, int out_size, void* d_ws, size_t ws_size,
                              hipStream_t stream) {
    const float* in  = (const float*)d_in[0];   // (8, 64, 16, 32, 32) fp32
    const float* emb = (const float*)d_in[1];   // (1024, 64) fp32
    float* out = (float*)d_out;
    _Float16* Ef   = (_Float16*)d_ws;                       // 64 tiles * 4 KB = 256 KB
    float*    me2h = (float*)((char*)d_ws + 262144);        // 1024 floats = -2048*||e||^2

    vq_prep<<<KDIM / 16, 256, 0, stream>>>(emb, Ef, me2h, out);
    vq_main<<<NTOT / BN, 256, 0, stream>>>(in, emb, Ef, me2h, out);
}